// Round 22
// baseline (10664.577 us; speedup 1.0000x reference)
//
#include <hip/hip_runtime.h>
#include <math.h>

#define QQ 512
#define NN 1000
#define HHID 1024
#define HPAD 1024   // padded row stride for h trajectories (X uses 1024 too)
#define CCON 128
#define G4 4000
#define LAYERS 8
#define TC 64                       // timestep chunk
#define CHUNKS (QQ / TC)            // 8
#define CONC 4      // max concurrent pairs: 252x1024-thr blocks = 1/CU (law)
#define LBLK 63     // blocks per pair, 1024 thr, 1 neuron/wave

typedef unsigned long long ull;

__device__ inline float wred_min(float v){ for(int o=32;o;o>>=1) v=fminf(v,__shfl_xor(v,o)); return v; }
__device__ inline float wred_max(float v){ for(int o=32;o;o>>=1) v=fmaxf(v,__shfl_xor(v,o)); return v; }
__device__ inline float wred_sum(float v){ for(int o=32;o;o>>=1) v+=__shfl_xor(v,o); return v; }

// ---------------- generic NT GEMM (X prologue only) ----------------
__global__ __launch_bounds__(256) void gemm_nt(
    const float* __restrict__ A, const float* __restrict__ B,
    const float* __restrict__ bias1,
    float* __restrict__ C, int M, int K, int R, int lda, int ldc) {
  __shared__ float As[16][65];
  __shared__ float Bs[16][65];
  int tid = threadIdx.x;
  int tx = tid & 15, ty = tid >> 4;
  int m0 = blockIdx.y * 64, r0 = blockIdx.x * 64;
  float acc[4][4] = {};
  for (int k0 = 0; k0 < K; k0 += 16) {
#pragma unroll
    for (int i = 0; i < 4; i++) {
      int idx = tid + 256 * i;
      int ml = idx >> 4, kl = idx & 15;
      int m = m0 + ml, k = k0 + kl;
      As[kl][ml] = (m < M && k < K) ? A[(size_t)m * lda + k] : 0.f;
      int r = r0 + ml;
      Bs[kl][ml] = (r < R && k < K) ? B[(size_t)r * K + k] : 0.f;
    }
    __syncthreads();
#pragma unroll
    for (int kk = 0; kk < 16; kk++) {
      float a[4], b[4];
#pragma unroll
      for (int i = 0; i < 4; i++) a[i] = As[kk][ty * 4 + i];
#pragma unroll
      for (int j = 0; j < 4; j++) b[j] = Bs[kk][tx * 4 + j];
#pragma unroll
      for (int i = 0; i < 4; i++)
#pragma unroll
        for (int j = 0; j < 4; j++) acc[i][j] += a[i] * b[j];
    }
    __syncthreads();
  }
#pragma unroll
  for (int i = 0; i < 4; i++) {
    int m = m0 + ty * 4 + i;
    if (m >= M) continue;
#pragma unroll
    for (int j = 0; j < 4; j++) {
      int r = r0 + tx * 4 + j;
      if (r >= R) continue;
      float v = acc[i][j];
      if (bias1) v += bias1[r];
      C[(size_t)m * ldc + r] = v;
    }
  }
}

// ---------------- fused per-stage recurrence (gates + TC steps) ----------
// Round-21 stamped-h body; Phase A register-blocked: 512 compute threads x
// 8 outputs (2 timesteps share every Bs read) -> 12 LDS b128 reads/output
// (was 20), tile fills vectorized (float4 / ulonglong2).
// Recurrence sync: stamped 64-bit h atoms {stamp=t+1 | fp32}; consumers
// poll own slot (stamp==t -> value valid). No flags, no producer vmcnt.
// Replay-safe: Hall64 zeroed every launch. W_hh preload AFTER Phase A +
// immediate pin (round-19 spill lesson). No fences (round-3 lesson).
struct RPair { const float* HinF;            // layer 0: X (plain fp32)
               const ull* Hin64;             // layers>0: stamped h of l-1
               const float* Wih; const float* b1; const float* b2;
               const float* Whh; ull* Hout64;
               float* Call; int t0; int kin; };
struct RArgs { RPair p[CONC]; };

__global__ __launch_bounds__(1024, 4) void lstm_stage(RArgs args) {
  RPair rp = args.p[blockIdx.y];
  __shared__ __align__(16) float As[64][68];
  __shared__ __align__(16) float Bs[64][68];
  __shared__ float gl[TC * 64];   // gates: gl[tt*64 + q*16 + w]
  __shared__ float hs[2][1024];   // parity-double-buffered h broadcast
  int tid = threadIdx.x;
  int wave = tid >> 6, lane = tid & 63;
  int n = blockIdx.x * 16 + wave;
  bool active = (n < NN);
  int kin = rp.kin;               // 1024 for layer 0 (X), 1000 otherwise
  int t0 = rp.t0;

  if (tid >= NN) { hs[0][tid] = 0.f; hs[1][tid] = 0.f; }  // zero pads once

  // ---- Phase A: register-blocked tiled GEMM for input-side gates ----
  {
    int w16 = tid & 15;
    int ttA = (tid >> 4) & 31;        // compute thread: tts {ttA, ttA+32}
    bool act = (tid < 512);
    int nn = blockIdx.x * 16 + w16;
    float acc0[4] = {0.f, 0.f, 0.f, 0.f};
    float acc1[4] = {0.f, 0.f, 0.f, 0.f};
    float pbq[4];
#pragma unroll
    for (int q = 0; q < 4; q++)
      pbq[q] = (nn < NN) ? rp.b1[q * NN + nn] + rp.b2[q * NN + nn] : 0.f;
    int ldr = tid >> 4, ldc4 = tid & 15;   // tile-load coords (all 1024 thr)
    int qb = ldr >> 4, nb = blockIdx.x * 16 + (ldr & 15);
    for (int k0 = 0; k0 < kin; k0 += 64) {
      int k = k0 + ldc4 * 4;
      // As row ldr, 4 elements
      float4 av;
      if (kin == HHID) {                   // layer 0: X plain fp32
        av = *(const float4*)&rp.HinF[(size_t)(t0 + ldr) * HPAD + k];
      } else if (k + 3 < kin) {            // stamped h, fast path
        const ull* p = &rp.Hin64[(size_t)(t0 + ldr) * HPAD + k];
        ulonglong2 u0 = *(const ulonglong2*)&p[0];
        ulonglong2 u1 = *(const ulonglong2*)&p[2];
        av.x = __uint_as_float((unsigned)u0.x);
        av.y = __uint_as_float((unsigned)u0.y);
        av.z = __uint_as_float((unsigned)u1.x);
        av.w = __uint_as_float((unsigned)u1.y);
      } else {
        float* f = (float*)&av;
#pragma unroll
        for (int e = 0; e < 4; e++)
          f[e] = (k + e < kin)
              ? __uint_as_float(
                    (unsigned)rp.Hin64[(size_t)(t0 + ldr) * HPAD + k + e])
              : 0.f;
      }
      *(float4*)&As[ldr][ldc4 * 4] = av;
      // Bs row ldr (gate-row qb, neuron nb), 4 elements
      float4 bv = {0.f, 0.f, 0.f, 0.f};
      if (nb < NN) {
        if (k + 3 < kin) {
          bv = *(const float4*)&rp.Wih[(size_t)(qb * NN + nb) * kin + k];
        } else {
          float* f = (float*)&bv;
#pragma unroll
          for (int e = 0; e < 4; e++)
            if (k + e < kin)
              f[e] = rp.Wih[(size_t)(qb * NN + nb) * kin + k + e];
        }
      }
      *(float4*)&Bs[ldr][ldc4 * 4] = bv;
      __syncthreads();
      if (act) {
#pragma unroll
        for (int kk4 = 0; kk4 < 16; kk4++) {
          float4 a0 = *(const float4*)&As[ttA][kk4 * 4];
          float4 a1 = *(const float4*)&As[ttA + 32][kk4 * 4];
#pragma unroll
          for (int q = 0; q < 4; q++) {
            float4 b = *(const float4*)&Bs[q * 16 + w16][kk4 * 4];
            acc0[q] += a0.x * b.x + a0.y * b.y + a0.z * b.z + a0.w * b.w;
            acc1[q] += a1.x * b.x + a1.y * b.y + a1.z * b.z + a1.w * b.w;
          }
        }
      }
      __syncthreads();
    }
    if (act) {
#pragma unroll
      for (int q = 0; q < 4; q++) {
        gl[ttA * 64 + q * 16 + w16] = acc0[q] + pbq[q];
        gl[(ttA + 32) * 64 + q * 16 + w16] = acc1[q] + pbq[q];
      }
    }
  }

  // ---- Phase B: W_hh preload (after Phase A) + immediate pin ----
  float wreg[4][16];
  if (active) {
#pragma unroll
    for (int q = 0; q < 4; q++) {
      const float* wr = rp.Whh + (size_t)(q * NN + n) * NN;
#pragma unroll
      for (int it = 0; it < 16; it++) {
        int k = it * 64 + lane;
        wreg[q][it] = (k < NN) ? wr[k] : 0.f;
      }
    }
  } else {
#pragma unroll
    for (int q = 0; q < 4; q++)
#pragma unroll
      for (int it = 0; it < 16; it++) wreg[q][it] = 0.f;
  }
#pragma unroll
  for (int q = 0; q < 4; q++)
#pragma unroll
    for (int it = 0; it < 16; it++)
      asm volatile("" : "+v"(wreg[q][it]));  // keep register-resident

  __syncthreads();  // gl complete, hs pads visible

  float creg = 0.f;
  if (t0 > 0 && active) creg = rp.Call[n];  // prev-dispatch data, plain load

  // ---- recurrence: stamped-poll, ONE barrier per step ----
  for (int tt = 0; tt < TC; tt++) {
    int t = t0 + tt;
    float* hb = hs[t & 1];
    if (t > 0 && tid < NN) {
      const ull* src = rp.Hout64 + (size_t)(t - 1) * HPAD + tid;
      for (;;) {
        ull v = __hip_atomic_load(src, __ATOMIC_RELAXED,
                                  __HIP_MEMORY_SCOPE_AGENT);
        if ((unsigned)(v >> 32) == (unsigned)t) {  // stamp t => h[t-1]
          hb[tid] = __uint_as_float((unsigned)v);
          break;
        }
        __builtin_amdgcn_s_sleep(1);
      }
    }
    __syncthreads();  // hb ready; prev parity buffer reads all done
    if (active) {
      float g0 = gl[tt * 64 + wave];
      float g1 = gl[tt * 64 + 16 + wave];
      float g2 = gl[tt * 64 + 32 + wave];
      float g3 = gl[tt * 64 + 48 + wave];
      if (t > 0) {
        float a0 = 0.f, a1 = 0.f, a2 = 0.f, a3 = 0.f;
#pragma unroll
        for (int it = 0; it < 16; it++) {
          float hv = hb[it * 64 + lane];
          a0 += wreg[0][it] * hv;
          a1 += wreg[1][it] * hv;
          a2 += wreg[2][it] * hv;
          a3 += wreg[3][it] * hv;
        }
#pragma unroll
        for (int o = 32; o; o >>= 1) {
          a0 += __shfl_xor(a0, o);
          a1 += __shfl_xor(a1, o);
          a2 += __shfl_xor(a2, o);
          a3 += __shfl_xor(a3, o);
        }
        g0 += a0; g1 += a1; g2 += a2; g3 += a3;
      }
      float ii = 1.f / (1.f + expf(-g0));
      float ff = 1.f / (1.f + expf(-g1));
      float gg = tanhf(g2);
      float oo = 1.f / (1.f + expf(-g3));
      creg = ff * creg + ii * gg;
      float h = oo * tanhf(creg);
      if (lane == 0) {
        ull pkt = ((ull)(unsigned)(t + 1) << 32) | (ull)__float_as_uint(h);
        __hip_atomic_store(&rp.Hout64[(size_t)t * HPAD + n], pkt,
                           __ATOMIC_RELAXED, __HIP_MEMORY_SCOPE_AGENT);
      }
    }
    // no vmcnt, no flag, no second barrier: the stamped store IS the signal
  }
  if (active && lane == 0)
    __hip_atomic_store(&rp.Call[n], creg, __ATOMIC_RELAXED,
                       __HIP_MEMORY_SCOPE_AGENT);
}

// ---------------- epilogue (reads stamped H7, low word) ----------------
__global__ __launch_bounds__(256) void epilogue_out(
    const ull* __restrict__ H7,     // [QQ, HPAD] stamped
    const float* __restrict__ Wlin, const float* __restrict__ blin,
    const int* __restrict__ ccol, const float* __restrict__ Dnz,
    float* __restrict__ out,        // [QQ, NN]
    float* __restrict__ irbuf, float* __restrict__ mnirbuf) {
  int t = blockIdx.x, tid = threadIdx.x;
  int wave = tid >> 6, lane = tid & 63;
  __shared__ float hbuf[NN];
  __shared__ float smin[4], smax[4];
  __shared__ float bc[2];
  float lmin = 3.4e38f, lmax = -3.4e38f;
  for (int i = tid; i < NN; i += 256) {
    float v = __uint_as_float((unsigned)H7[(size_t)t * HPAD + i]);
    hbuf[i] = v;
    lmin = fminf(lmin, v); lmax = fmaxf(lmax, v);
  }
  lmin = wred_min(lmin); lmax = wred_max(lmax);
  if (lane == 0) { smin[wave] = lmin; smax[wave] = lmax; }
  __syncthreads();
  if (tid == 0) {
    bc[0] = fminf(fminf(smin[0], smin[1]), fminf(smin[2], smin[3]));
    bc[1] = fmaxf(fmaxf(smax[0], smax[1]), fmaxf(smax[2], smax[3]));
  }
  __syncthreads();
  float hmn = bc[0], hmx = bc[1];
  float clo = 3.4e38f, chi = -3.4e38f;
  if (tid < CCON) {
    float w = Wlin[tid], b = blin[tid];
    clo = b + fminf(w * hmn, w * hmx);
    chi = b + fmaxf(w * hmn, w * hmx);
  }
  clo = wred_min(clo); chi = wred_max(chi);
  __syncthreads();  // smin/smax reused below
  if (lane == 0) { smin[wave] = clo; smax[wave] = chi; }
  __syncthreads();
  if (tid == 0) {
    float mn = fminf(fminf(smin[0], smin[1]), fminf(smin[2], smin[3]));
    float mx = fmaxf(fmaxf(smax[0], smax[1]), fmaxf(smax[2], smax[3]));
    float ir = 1.f / (mx - mn);
    bc[0] = mn; bc[1] = ir;
    irbuf[t] = ir;
    mnirbuf[t] = mn * ir;
  }
  __syncthreads();
  float mn = bc[0], ir = bc[1];
  int cc = ccol[t];
  float wcc = Wlin[cc], bcc = blin[cc], d = Dnz[t];
  for (int n = tid; n < NN; n += 256) {
    float s = (hbuf[n] * wcc + bcc - mn) * ir;
    out[(size_t)t * NN + n] = fmaxf(0.25f, 1.f - expf(-10.f * (s - d)));
  }
}

__global__ void reduce_scalars(const float* __restrict__ ir,
                               const float* __restrict__ mnir,
                               float* __restrict__ scal) {
  int tid = threadIdx.x;  // 512
  int wave = tid >> 6, lane = tid & 63;
  __shared__ float s1[8], s2[8];
  float a = ir[tid], b = mnir[tid];
  a = wred_sum(a); b = wred_sum(b);
  if (lane == 0) { s1[wave] = a; s2[wave] = b; }
  __syncthreads();
  if (tid == 0) {
    float A = 0.f, B = 0.f;
    for (int i = 0; i < 8; i++) { A += s1[i]; B += s2[i]; }
    scal[0] = A; scal[1] = B;
  }
}

__global__ void accum_A(const ull* __restrict__ H7,
                        const float* __restrict__ ir,
                        float* __restrict__ Avec) {
  int n = blockIdx.x * 256 + threadIdx.x;
  if (n < NN) {
    float acc = 0.f;
    for (int t = 0; t < QQ; t++)
      acc += __uint_as_float((unsigned)H7[(size_t)t * HPAD + n]) * ir[t];
    Avec[n] = acc;
  }
}

__global__ void skills_out(const float* __restrict__ Avec,
                           const float* __restrict__ Wlin,
                           const float* __restrict__ blin,
                           const float* __restrict__ scal,
                           float* __restrict__ out) {  // [NN, CCON]
  int idx = blockIdx.x * 256 + threadIdx.x;
  if (idx < NN * CCON) {
    int n = idx >> 7, c = idx & 127;
    out[idx] = (Wlin[c] * Avec[n] + blin[c] * scal[0] - scal[1]) * (1.f / (float)QQ);
  }
}

extern "C" void kernel_launch(void* const* d_in, const int* in_sizes, int n_in,
                              void* d_out, int out_size, void* d_ws, size_t ws_size,
                              hipStream_t stream) {
  const float* inputs = (const float*)d_in[0];
  const int*   ccol   = (const int*)d_in[1];
  const float* W_inp  = (const float*)d_in[2];
  const float* b_inp  = (const float*)d_in[3];
  const float* W_ih0  = (const float*)d_in[4];
  const float* W_hh0  = (const float*)d_in[5];
  const float* b_ih0  = (const float*)d_in[6];
  const float* b_hh0  = (const float*)d_in[7];
  const float* W_ih   = (const float*)d_in[8];   // [7, 4000, 1000]
  const float* W_hh   = (const float*)d_in[9];   // [7, 4000, 1000]
  const float* b_ih   = (const float*)d_in[10];  // [7, 4000]
  const float* b_hh   = (const float*)d_in[11];  // [7, 4000]
  const float* W_lin  = (const float*)d_in[12];  // [128]
  const float* b_lin  = (const float*)d_in[13];  // [128]
  const float* D_nz   = (const float*)d_in[14];  // [512]

  float* ws = (float*)d_ws;
  float* X     = ws;                          // [512,1024] fp32, 2 MB
  ull*   Hall  = (ull*)(X + (size_t)QQ * HPAD); // [8][512][1024] stamped, 32 MB
  float* tail  = (float*)(Hall + (size_t)LAYERS * QQ * HPAD);
  float* Call  = tail;                        // [8][1024]
  float* irb   = Call + LAYERS * HPAD;        // [512]
  float* mnir  = irb + QQ;                    // [512]
  float* Avec  = mnir + QQ;                   // [1024]
  float* scal  = Avec + 1024;                 // [2] (+pad)

  float* out_main   = (float*)d_out;            // [512,1000]
  float* out_skills = (float*)d_out + QQ * NN;  // [1000,128]

  // Zero ALL stamps every launch (graph-captured): prior-replay/poison
  // stamps can never satisfy a poll.
  hipMemsetAsync(Hall, 0, (size_t)LAYERS * QQ * HPAD * sizeof(ull), stream);

  // X = inputs @ W_inp^T + b_inp   (M=512, K=1000, R=1024, ldc=HPAD)
  gemm_nt<<<dim3(HPAD / 64, QQ / 64), 256, 0, stream>>>(
      inputs, W_inp, b_inp, X, QQ, NN, HPAD, NN, HPAD);

  // List-scheduled wavefront, capped at CONC pairs/stage (19 stages is
  // provably optimal for CONC=4, TC=64).
  bool donep[LAYERS][CHUNKS] = {};
  int remaining = LAYERS * CHUNKS;
  while (remaining > 0) {
    int pl[CONC], pcid[CONC];
    bool sel[LAYERS][CHUNKS] = {};
    int np = 0;
    for (int pick = 0; pick < CONC; pick++) {
      int bl = -1, bc = -1, bkey = 1 << 30;
      for (int l = 0; l < LAYERS; l++)
        for (int c = 0; c < CHUNKS; c++) {
          if (donep[l][c] || sel[l][c]) continue;
          if (l > 0 && !donep[l - 1][c]) continue;
          if (c > 0 && !donep[l][c - 1]) continue;
          int key = (l + c) * 16 + (LAYERS - 1 - l);
          if (key < bkey) { bkey = key; bl = l; bc = c; }
        }
      if (bl < 0) break;
      sel[bl][bc] = true; pl[np] = bl; pcid[np] = bc; np++;
    }
    RArgs ra;
    for (int i = 0; i < np; i++) {
      int l = pl[i], c = pcid[i];
      RPair& r = ra.p[i];
      if (l == 0) {
        r.HinF = X; r.Hin64 = nullptr;
        r.Wih = W_ih0; r.b1 = b_ih0; r.b2 = b_hh0;
        r.Whh = W_hh0; r.kin = HHID;
      } else {
        r.HinF = nullptr;
        r.Hin64 = Hall + (size_t)(l - 1) * QQ * HPAD;
        r.Wih = W_ih + (size_t)(l - 1) * G4 * NN;
        r.b1 = b_ih + (size_t)(l - 1) * G4;
        r.b2 = b_hh + (size_t)(l - 1) * G4;
        r.Whh = W_hh + (size_t)(l - 1) * G4 * NN;
        r.kin = NN;
      }
      r.Hout64 = Hall + (size_t)l * QQ * HPAD;
      r.Call = Call + l * HPAD;
      r.t0 = c * TC;
    }
    for (int i = np; i < CONC; i++) ra.p[i] = ra.p[0];
    lstm_stage<<<dim3(LBLK, np), 1024, 0, stream>>>(ra);
    for (int i = 0; i < np; i++) donep[pl[i]][pcid[i]] = true;
    remaining -= np;
  }

  const ull* H7 = Hall + (size_t)7 * QQ * HPAD;
  epilogue_out<<<QQ, 256, 0, stream>>>(H7, W_lin, b_lin, ccol, D_nz,
                                       out_main, irb, mnir);
  reduce_scalars<<<1, 512, 0, stream>>>(irb, mnir, scal);
  accum_A<<<4, 256, 0, stream>>>(H7, irb, Avec);
  skills_out<<<(NN * CCON) / 256, 256, 0, stream>>>(Avec, W_lin, b_lin, scal,
                                                    out_skills);
}

// Round 23
// 6802.876 us; speedup vs baseline: 1.5677x; 1.5677x over previous
//
#include <hip/hip_runtime.h>
#include <math.h>

#define QQ 512
#define NN 1000
#define HHID 1024
#define HPAD 1024   // padded row stride for h trajectories (X uses 1024 too)
#define CCON 128
#define G4 4000
#define LAYERS 8
#define TC 64                       // timestep chunk
#define CHUNKS (QQ / TC)            // 8
#define CONC 4      // max concurrent pairs: 252x1024-thr blocks = 1/CU (law)
#define LBLK 63     // blocks per pair, 1024 thr, 1 neuron/wave

typedef unsigned long long ull;

__device__ inline float wred_min(float v){ for(int o=32;o;o>>=1) v=fminf(v,__shfl_xor(v,o)); return v; }
__device__ inline float wred_max(float v){ for(int o=32;o;o>>=1) v=fmaxf(v,__shfl_xor(v,o)); return v; }
__device__ inline float wred_sum(float v){ for(int o=32;o;o>>=1) v+=__shfl_xor(v,o); return v; }

// ---------------- generic NT GEMM (X prologue only) ----------------
__global__ __launch_bounds__(256) void gemm_nt(
    const float* __restrict__ A, const float* __restrict__ B,
    const float* __restrict__ bias1,
    float* __restrict__ C, int M, int K, int R, int lda, int ldc) {
  __shared__ float As[16][65];
  __shared__ float Bs[16][65];
  int tid = threadIdx.x;
  int tx = tid & 15, ty = tid >> 4;
  int m0 = blockIdx.y * 64, r0 = blockIdx.x * 64;
  float acc[4][4] = {};
  for (int k0 = 0; k0 < K; k0 += 16) {
#pragma unroll
    for (int i = 0; i < 4; i++) {
      int idx = tid + 256 * i;
      int ml = idx >> 4, kl = idx & 15;
      int m = m0 + ml, k = k0 + kl;
      As[kl][ml] = (m < M && k < K) ? A[(size_t)m * lda + k] : 0.f;
      int r = r0 + ml;
      Bs[kl][ml] = (r < R && k < K) ? B[(size_t)r * K + k] : 0.f;
    }
    __syncthreads();
#pragma unroll
    for (int kk = 0; kk < 16; kk++) {
      float a[4], b[4];
#pragma unroll
      for (int i = 0; i < 4; i++) a[i] = As[kk][ty * 4 + i];
#pragma unroll
      for (int j = 0; j < 4; j++) b[j] = Bs[kk][tx * 4 + j];
#pragma unroll
      for (int i = 0; i < 4; i++)
#pragma unroll
        for (int j = 0; j < 4; j++) acc[i][j] += a[i] * b[j];
    }
    __syncthreads();
  }
#pragma unroll
  for (int i = 0; i < 4; i++) {
    int m = m0 + ty * 4 + i;
    if (m >= M) continue;
#pragma unroll
    for (int j = 0; j < 4; j++) {
      int r = r0 + tx * 4 + j;
      if (r >= R) continue;
      float v = acc[i][j];
      if (bias1) v += bias1[r];
      C[(size_t)m * ldc + r] = v;
    }
  }
}

// ---------------- fused per-stage recurrence (gates + TC steps) ----------
// Round-21 stamped-h body; ONLY delta: Phase A tile fills vectorized
// (1 float4 / 2 ulonglong2 global load + 1 b128 LDS write per array per
// thread, was 4 scalar each). MAC loop identical to r21 (4 accumulators
// only -- any extra cross-barrier live state spills, r19/r22 lesson).
// Recurrence sync: stamped 64-bit h atoms {stamp=t+1 | fp32}; consumers
// poll own slot (stamp==t -> value valid). No flags, no producer vmcnt.
// Replay-safe: Hall64 zeroed every launch. W_hh preload AFTER Phase A +
// immediate pin. No fences (agent acquire fence = buffer_inv, round-3).
struct RPair { const float* HinF;            // layer 0: X (plain fp32)
               const ull* Hin64;             // layers>0: stamped h of l-1
               const float* Wih; const float* b1; const float* b2;
               const float* Whh; ull* Hout64;
               float* Call; int t0; int kin; };
struct RArgs { RPair p[CONC]; };

__global__ __launch_bounds__(1024, 4) void lstm_stage(RArgs args) {
  RPair rp = args.p[blockIdx.y];
  __shared__ __align__(16) float As[64][68];
  __shared__ __align__(16) float Bs[64][68];
  __shared__ float gl[TC * 64];   // gates: gl[tt*64 + q*16 + w]
  __shared__ float hs[2][1024];   // parity-double-buffered h broadcast
  int tid = threadIdx.x;
  int wave = tid >> 6, lane = tid & 63;
  int n = blockIdx.x * 16 + wave;
  bool active = (n < NN);
  int kin = rp.kin;               // 1024 for layer 0 (X), 1000 otherwise
  int t0 = rp.t0;

  if (tid >= NN) { hs[0][tid] = 0.f; hs[1][tid] = 0.f; }  // zero pads once

  // ---- Phase A: tiled GEMM for input-side gates (vectorized fills) ----
  {
    int ttA = tid >> 4;           // 0..63 timestep within chunk
    int w16 = tid & 15;           // neuron within block
    int nn = blockIdx.x * 16 + w16;
    float accq[4] = {0.f, 0.f, 0.f, 0.f};
    float pbq[4];
#pragma unroll
    for (int q = 0; q < 4; q++)
      pbq[q] = (nn < NN) ? rp.b1[q * NN + nn] + rp.b2[q * NN + nn] : 0.f;
    int ldr = tid >> 4, ldc4 = tid & 15;   // fill coords: row, col-group
    int qb = ldr >> 4, nb = blockIdx.x * 16 + (ldr & 15);
    for (int k0 = 0; k0 < kin; k0 += 64) {
      int k = k0 + ldc4 * 4;
      // As row ldr: 4 elements in one shot
      float4 av;
      if (kin == HHID) {                   // layer 0: X plain fp32
        av = *(const float4*)&rp.HinF[(size_t)(t0 + ldr) * HPAD + k];
      } else if (k + 3 < kin) {            // stamped h fast path
        const ull* p = &rp.Hin64[(size_t)(t0 + ldr) * HPAD + k];
        ulonglong2 u0 = *(const ulonglong2*)&p[0];
        ulonglong2 u1 = *(const ulonglong2*)&p[2];
        av.x = __uint_as_float((unsigned)u0.x);
        av.y = __uint_as_float((unsigned)u0.y);
        av.z = __uint_as_float((unsigned)u1.x);
        av.w = __uint_as_float((unsigned)u1.y);
      } else {
        float* f = (float*)&av;
#pragma unroll
        for (int e = 0; e < 4; e++)
          f[e] = (k + e < kin)
              ? __uint_as_float(
                    (unsigned)rp.Hin64[(size_t)(t0 + ldr) * HPAD + k + e])
              : 0.f;
      }
      *(float4*)&As[ldr][ldc4 * 4] = av;
      // Bs row ldr (gate qb, neuron nb): 4 elements in one shot
      float4 bv = {0.f, 0.f, 0.f, 0.f};
      if (nb < NN) {
        if (k + 3 < kin) {
          bv = *(const float4*)&rp.Wih[(size_t)(qb * NN + nb) * kin + k];
        } else {
          float* f = (float*)&bv;
#pragma unroll
          for (int e = 0; e < 4; e++)
            if (k + e < kin)
              f[e] = rp.Wih[(size_t)(qb * NN + nb) * kin + k + e];
        }
      }
      *(float4*)&Bs[ldr][ldc4 * 4] = bv;
      __syncthreads();
      // MAC: identical to round 21 (4 accumulators, float4 LDS reads)
#pragma unroll
      for (int kk = 0; kk < 64; kk += 4) {
        float4 a = *(const float4*)&As[ttA][kk];
#pragma unroll
        for (int q = 0; q < 4; q++) {
          float4 b = *(const float4*)&Bs[q * 16 + w16][kk];
          accq[q] += a.x * b.x + a.y * b.y + a.z * b.z + a.w * b.w;
        }
      }
      __syncthreads();
    }
#pragma unroll
    for (int q = 0; q < 4; q++)
      gl[ttA * 64 + q * 16 + w16] = accq[q] + pbq[q];
  }

  // ---- Phase B: W_hh preload (after Phase A) + immediate pin ----
  float wreg[4][16];
  if (active) {
#pragma unroll
    for (int q = 0; q < 4; q++) {
      const float* wr = rp.Whh + (size_t)(q * NN + n) * NN;
#pragma unroll
      for (int it = 0; it < 16; it++) {
        int k = it * 64 + lane;
        wreg[q][it] = (k < NN) ? wr[k] : 0.f;
      }
    }
  } else {
#pragma unroll
    for (int q = 0; q < 4; q++)
#pragma unroll
      for (int it = 0; it < 16; it++) wreg[q][it] = 0.f;
  }
#pragma unroll
  for (int q = 0; q < 4; q++)
#pragma unroll
    for (int it = 0; it < 16; it++)
      asm volatile("" : "+v"(wreg[q][it]));  // keep register-resident

  __syncthreads();  // gl complete, hs pads visible

  float creg = 0.f;
  if (t0 > 0 && active) creg = rp.Call[n];  // prev-dispatch data, plain load

  // ---- recurrence: stamped-poll, ONE barrier per step ----
  for (int tt = 0; tt < TC; tt++) {
    int t = t0 + tt;
    float* hb = hs[t & 1];
    if (t > 0 && tid < NN) {
      const ull* src = rp.Hout64 + (size_t)(t - 1) * HPAD + tid;
      for (;;) {
        ull v = __hip_atomic_load(src, __ATOMIC_RELAXED,
                                  __HIP_MEMORY_SCOPE_AGENT);
        if ((unsigned)(v >> 32) == (unsigned)t) {  // stamp t => h[t-1]
          hb[tid] = __uint_as_float((unsigned)v);
          break;
        }
        __builtin_amdgcn_s_sleep(1);
      }
    }
    __syncthreads();  // hb ready; prev parity buffer reads all done
    if (active) {
      float g0 = gl[tt * 64 + wave];
      float g1 = gl[tt * 64 + 16 + wave];
      float g2 = gl[tt * 64 + 32 + wave];
      float g3 = gl[tt * 64 + 48 + wave];
      if (t > 0) {
        float a0 = 0.f, a1 = 0.f, a2 = 0.f, a3 = 0.f;
#pragma unroll
        for (int it = 0; it < 16; it++) {
          float hv = hb[it * 64 + lane];
          a0 += wreg[0][it] * hv;
          a1 += wreg[1][it] * hv;
          a2 += wreg[2][it] * hv;
          a3 += wreg[3][it] * hv;
        }
#pragma unroll
        for (int o = 32; o; o >>= 1) {
          a0 += __shfl_xor(a0, o);
          a1 += __shfl_xor(a1, o);
          a2 += __shfl_xor(a2, o);
          a3 += __shfl_xor(a3, o);
        }
        g0 += a0; g1 += a1; g2 += a2; g3 += a3;
      }
      float ii = 1.f / (1.f + expf(-g0));
      float ff = 1.f / (1.f + expf(-g1));
      float gg = tanhf(g2);
      float oo = 1.f / (1.f + expf(-g3));
      creg = ff * creg + ii * gg;
      float h = oo * tanhf(creg);
      if (lane == 0) {
        ull pkt = ((ull)(unsigned)(t + 1) << 32) | (ull)__float_as_uint(h);
        __hip_atomic_store(&rp.Hout64[(size_t)t * HPAD + n], pkt,
                           __ATOMIC_RELAXED, __HIP_MEMORY_SCOPE_AGENT);
      }
    }
    // no vmcnt, no flag, no second barrier: the stamped store IS the signal
  }
  if (active && lane == 0)
    __hip_atomic_store(&rp.Call[n], creg, __ATOMIC_RELAXED,
                       __HIP_MEMORY_SCOPE_AGENT);
}

// ---------------- epilogue (reads stamped H7, low word) ----------------
__global__ __launch_bounds__(256) void epilogue_out(
    const ull* __restrict__ H7,     // [QQ, HPAD] stamped
    const float* __restrict__ Wlin, const float* __restrict__ blin,
    const int* __restrict__ ccol, const float* __restrict__ Dnz,
    float* __restrict__ out,        // [QQ, NN]
    float* __restrict__ irbuf, float* __restrict__ mnirbuf) {
  int t = blockIdx.x, tid = threadIdx.x;
  int wave = tid >> 6, lane = tid & 63;
  __shared__ float hbuf[NN];
  __shared__ float smin[4], smax[4];
  __shared__ float bc[2];
  float lmin = 3.4e38f, lmax = -3.4e38f;
  for (int i = tid; i < NN; i += 256) {
    float v = __uint_as_float((unsigned)H7[(size_t)t * HPAD + i]);
    hbuf[i] = v;
    lmin = fminf(lmin, v); lmax = fmaxf(lmax, v);
  }
  lmin = wred_min(lmin); lmax = wred_max(lmax);
  if (lane == 0) { smin[wave] = lmin; smax[wave] = lmax; }
  __syncthreads();
  if (tid == 0) {
    bc[0] = fminf(fminf(smin[0], smin[1]), fminf(smin[2], smin[3]));
    bc[1] = fmaxf(fmaxf(smax[0], smax[1]), fmaxf(smax[2], smax[3]));
  }
  __syncthreads();
  float hmn = bc[0], hmx = bc[1];
  float clo = 3.4e38f, chi = -3.4e38f;
  if (tid < CCON) {
    float w = Wlin[tid], b = blin[tid];
    clo = b + fminf(w * hmn, w * hmx);
    chi = b + fmaxf(w * hmn, w * hmx);
  }
  clo = wred_min(clo); chi = wred_max(chi);
  __syncthreads();  // smin/smax reused below
  if (lane == 0) { smin[wave] = clo; smax[wave] = chi; }
  __syncthreads();
  if (tid == 0) {
    float mn = fminf(fminf(smin[0], smin[1]), fminf(smin[2], smin[3]));
    float mx = fmaxf(fmaxf(smax[0], smax[1]), fmaxf(smax[2], smax[3]));
    float ir = 1.f / (mx - mn);
    bc[0] = mn; bc[1] = ir;
    irbuf[t] = ir;
    mnirbuf[t] = mn * ir;
  }
  __syncthreads();
  float mn = bc[0], ir = bc[1];
  int cc = ccol[t];
  float wcc = Wlin[cc], bcc = blin[cc], d = Dnz[t];
  for (int n = tid; n < NN; n += 256) {
    float s = (hbuf[n] * wcc + bcc - mn) * ir;
    out[(size_t)t * NN + n] = fmaxf(0.25f, 1.f - expf(-10.f * (s - d)));
  }
}

__global__ void reduce_scalars(const float* __restrict__ ir,
                               const float* __restrict__ mnir,
                               float* __restrict__ scal) {
  int tid = threadIdx.x;  // 512
  int wave = tid >> 6, lane = tid & 63;
  __shared__ float s1[8], s2[8];
  float a = ir[tid], b = mnir[tid];
  a = wred_sum(a); b = wred_sum(b);
  if (lane == 0) { s1[wave] = a; s2[wave] = b; }
  __syncthreads();
  if (tid == 0) {
    float A = 0.f, B = 0.f;
    for (int i = 0; i < 8; i++) { A += s1[i]; B += s2[i]; }
    scal[0] = A; scal[1] = B;
  }
}

__global__ void accum_A(const ull* __restrict__ H7,
                        const float* __restrict__ ir,
                        float* __restrict__ Avec) {
  int n = blockIdx.x * 256 + threadIdx.x;
  if (n < NN) {
    float acc = 0.f;
    for (int t = 0; t < QQ; t++)
      acc += __uint_as_float((unsigned)H7[(size_t)t * HPAD + n]) * ir[t];
    Avec[n] = acc;
  }
}

__global__ void skills_out(const float* __restrict__ Avec,
                           const float* __restrict__ Wlin,
                           const float* __restrict__ blin,
                           const float* __restrict__ scal,
                           float* __restrict__ out) {  // [NN, CCON]
  int idx = blockIdx.x * 256 + threadIdx.x;
  if (idx < NN * CCON) {
    int n = idx >> 7, c = idx & 127;
    out[idx] = (Wlin[c] * Avec[n] + blin[c] * scal[0] - scal[1]) * (1.f / (float)QQ);
  }
}

extern "C" void kernel_launch(void* const* d_in, const int* in_sizes, int n_in,
                              void* d_out, int out_size, void* d_ws, size_t ws_size,
                              hipStream_t stream) {
  const float* inputs = (const float*)d_in[0];
  const int*   ccol   = (const int*)d_in[1];
  const float* W_inp  = (const float*)d_in[2];
  const float* b_inp  = (const float*)d_in[3];
  const float* W_ih0  = (const float*)d_in[4];
  const float* W_hh0  = (const float*)d_in[5];
  const float* b_ih0  = (const float*)d_in[6];
  const float* b_hh0  = (const float*)d_in[7];
  const float* W_ih   = (const float*)d_in[8];   // [7, 4000, 1000]
  const float* W_hh   = (const float*)d_in[9];   // [7, 4000, 1000]
  const float* b_ih   = (const float*)d_in[10];  // [7, 4000]
  const float* b_hh   = (const float*)d_in[11];  // [7, 4000]
  const float* W_lin  = (const float*)d_in[12];  // [128]
  const float* b_lin  = (const float*)d_in[13];  // [128]
  const float* D_nz   = (const float*)d_in[14];  // [512]

  float* ws = (float*)d_ws;
  float* X     = ws;                          // [512,1024] fp32, 2 MB
  ull*   Hall  = (ull*)(X + (size_t)QQ * HPAD); // [8][512][1024] stamped, 32 MB
  float* tail  = (float*)(Hall + (size_t)LAYERS * QQ * HPAD);
  float* Call  = tail;                        // [8][1024]
  float* irb   = Call + LAYERS * HPAD;        // [512]
  float* mnir  = irb + QQ;                    // [512]
  float* Avec  = mnir + QQ;                   // [1024]
  float* scal  = Avec + 1024;                 // [2] (+pad)

  float* out_main   = (float*)d_out;            // [512,1000]
  float* out_skills = (float*)d_out + QQ * NN;  // [1000,128]

  // Zero ALL stamps every launch (graph-captured): prior-replay/poison
  // stamps can never satisfy a poll.
  hipMemsetAsync(Hall, 0, (size_t)LAYERS * QQ * HPAD * sizeof(ull), stream);

  // X = inputs @ W_inp^T + b_inp   (M=512, K=1000, R=1024, ldc=HPAD)
  gemm_nt<<<dim3(HPAD / 64, QQ / 64), 256, 0, stream>>>(
      inputs, W_inp, b_inp, X, QQ, NN, HPAD, NN, HPAD);

  // List-scheduled wavefront, capped at CONC pairs/stage (19 stages is
  // provably optimal for CONC=4, TC=64).
  bool donep[LAYERS][CHUNKS] = {};
  int remaining = LAYERS * CHUNKS;
  while (remaining > 0) {
    int pl[CONC], pcid[CONC];
    bool sel[LAYERS][CHUNKS] = {};
    int np = 0;
    for (int pick = 0; pick < CONC; pick++) {
      int bl = -1, bc = -1, bkey = 1 << 30;
      for (int l = 0; l < LAYERS; l++)
        for (int c = 0; c < CHUNKS; c++) {
          if (donep[l][c] || sel[l][c]) continue;
          if (l > 0 && !donep[l - 1][c]) continue;
          if (c > 0 && !donep[l][c - 1]) continue;
          int key = (l + c) * 16 + (LAYERS - 1 - l);
          if (key < bkey) { bkey = key; bl = l; bc = c; }
        }
      if (bl < 0) break;
      sel[bl][bc] = true; pl[np] = bl; pcid[np] = bc; np++;
    }
    RArgs ra;
    for (int i = 0; i < np; i++) {
      int l = pl[i], c = pcid[i];
      RPair& r = ra.p[i];
      if (l == 0) {
        r.HinF = X; r.Hin64 = nullptr;
        r.Wih = W_ih0; r.b1 = b_ih0; r.b2 = b_hh0;
        r.Whh = W_hh0; r.kin = HHID;
      } else {
        r.HinF = nullptr;
        r.Hin64 = Hall + (size_t)(l - 1) * QQ * HPAD;
        r.Wih = W_ih + (size_t)(l - 1) * G4 * NN;
        r.b1 = b_ih + (size_t)(l - 1) * G4;
        r.b2 = b_hh + (size_t)(l - 1) * G4;
        r.Whh = W_hh + (size_t)(l - 1) * G4 * NN;
        r.kin = NN;
      }
      r.Hout64 = Hall + (size_t)l * QQ * HPAD;
      r.Call = Call + l * HPAD;
      r.t0 = c * TC;
    }
    for (int i = np; i < CONC; i++) ra.p[i] = ra.p[0];
    lstm_stage<<<dim3(LBLK, np), 1024, 0, stream>>>(ra);
    for (int i = 0; i < np; i++) donep[pl[i]][pcid[i]] = true;
    remaining -= np;
  }

  const ull* H7 = Hall + (size_t)7 * QQ * HPAD;
  epilogue_out<<<QQ, 256, 0, stream>>>(H7, W_lin, b_lin, ccol, D_nz,
                                       out_main, irb, mnir);
  reduce_scalars<<<1, 512, 0, stream>>>(irb, mnir, scal);
  accum_A<<<4, 256, 0, stream>>>(H7, irb, Avec);
  skills_out<<<(NN * CCON) / 256, 256, 0, stream>>>(Avec, W_lin, b_lin, scal,
                                                    out_skills);
}